// Round 17
// baseline (5523.351 us; speedup 1.0000x reference)
//
#include <hip/hip_runtime.h>
#include <hip/hip_bf16.h>
#include <cstring>
#include <cmath>

#define NBAT 32
#define LQ 30
#define NP 80
#define NSEGC 2560   // NBAT*NP chunk segments
#define DD 768
#define KC 6912      // 2304 * 3 precision parts
#define LB 94
#define FF 3072

typedef unsigned short u16;
typedef __attribute__((__ext_vector_type__(4))) float f32x4;
typedef __attribute__((__ext_vector_type__(8))) short s16x8;
typedef __attribute__((__ext_vector_type__(8))) _Float16 f16x8;

__constant__ float MU_C[11] = {1.0f,0.9f,0.7f,0.5f,0.3f,0.1f,-0.1f,-0.3f,-0.5f,-0.7f,-0.9f};

__device__ __forceinline__ float wsum(float v) {
#pragma unroll
  for (int o = 32; o; o >>= 1) v += __shfl_xor(v, o);
  return v;
}
__device__ __forceinline__ u16 f2b(float f) {
  __hip_bfloat16 h = __float2bfloat16(f);
  u16 u; __builtin_memcpy(&u, &h, 2); return u;
}
__device__ __forceinline__ float b2f(u16 u) {
  unsigned v = ((unsigned)u) << 16; float f; __builtin_memcpy(&f, &v, 4); return f;
}
__device__ __forceinline__ u16 h_bits(_Float16 h) { u16 u; __builtin_memcpy(&u, &h, 2); return u; }

__device__ __forceinline__ void gll16(const void* g, void* l) {
  __builtin_amdgcn_global_load_lds((const __attribute__((address_space(1))) unsigned*)g,
                                   (__attribute__((address_space(3))) unsigned*)l, 16, 0, 0);
}

// ---------------- mid 128x192 MFMA GEMM, 512 thr (8 waves x 64x48), BK=64, 2-phase dbuf ----------------
// R12-proven geometry: LDS 80KB -> 2 blocks/CU = 16 waves/CU (R13 lesson: 4-wave re-tile halved
// resident waves and lost more TLP than its LDS-read saving bought; wave count is first-order).
// rule-#21 XOR-swizzled LDS, XCD-chunked bijective swizzle, full-tile-ahead prefetch + counted
// vmcnt(5) (R10 lesson: never collapse prefetch distance). Identical per-element K-order.
// AMODE: 0 flat [M][K], 1 conv-im2col over [seg][66][2304]. DT: 0 bf16, 1 f16.
// EPI: 0 fp32; 1 bf16 gelu(acc+bias); 2 bf16 acc; 3 bf16 acc+bias.
template<int AMODE, int DT, int EPI>
__global__ __launch_bounds__(512) void gemm_mid(const u16* __restrict__ A, const u16* __restrict__ BT,
                                                void* __restrict__ Cv, const float* __restrict__ bias,
                                                int M, int N, int K)
{
  __shared__ __align__(16) u16 As[2][128*64];   // 32 KB
  __shared__ __align__(16) u16 Bs[2][192*64];   // 48 KB
  const int tid = threadIdx.x;
  const int lane = tid & 63;
  const int w = tid >> 6;          // 0..7

  const int NBY = N / 192;
  const int nb = gridDim.x;
  const int q8 = nb >> 3, r8 = nb & 7;
  const int xcd = blockIdx.x & 7, slot = blockIdx.x >> 3;
  const int base8 = (xcd < r8) ? xcd*(q8+1) : r8*(q8+1) + (xcd - r8)*q8;
  const int wk = base8 + slot;
  const long m0 = (long)(wk / NBY) * 128;
  const long n0 = (long)(wk % NBY) * 192;

  const int wr = (w >> 2) * 64;    // 0 or 64
  const int wc = (w & 3) * 48;     // 0,48,96,144

  const int lrow = lane >> 3;                  // 0..7
  const int scg  = (lane & 7) ^ lrow;          // inverse-swizzled global k-chunk

  long aoff[2], boff[3];
#pragma unroll
  for (int it = 0; it < 2; ++it) {
    const long ga = m0 + it*64 + w*8 + lrow;
    if (AMODE == 0) aoff[it] = ga * (long)K;
    else            aoff[it] = ((ga >> 6) * 66 + (ga & 63)) * 2304L;
  }
#pragma unroll
  for (int it = 0; it < 3; ++it)
    boff[it] = (long)(n0 + it*64 + w*8 + lrow) * (long)K;

  f32x4 acc[4][3] = {};

  const int T = K >> 6;
  // prologue: stage tile 0 (5 loads/wave)
#pragma unroll
  for (int it = 0; it < 2; ++it)
    gll16(A + aoff[it] + scg*8, &As[0][(it*64 + w*8) * 64]);
#pragma unroll
  for (int it = 0; it < 3; ++it)
    gll16(BT + boff[it] + scg*8, &Bs[0][(it*64 + w*8) * 64]);

  for (int t = 0; t < T; ++t) {
    const int cb = t & 1;
    if (t + 1 < T) {
      const int k1 = (t + 1) << 6;
#pragma unroll
      for (int it = 0; it < 2; ++it)
        gll16(A + aoff[it] + k1 + scg*8, &As[cb ^ 1][(it*64 + w*8) * 64]);
#pragma unroll
      for (int it = 0; it < 3; ++it)
        gll16(BT + boff[it] + k1 + scg*8, &Bs[cb ^ 1][(it*64 + w*8) * 64]);
      asm volatile("s_waitcnt vmcnt(5)" ::: "memory");   // tile-t loads done; 5 newer in flight
    } else {
      asm volatile("s_waitcnt vmcnt(0)" ::: "memory");
    }
    __builtin_amdgcn_s_barrier();
    __builtin_amdgcn_sched_barrier(0);
#pragma unroll
    for (int kk = 0; kk < 2; ++kk) {
      const int cc = kk*4 + (lane >> 4);
      const int sw = (cc ^ (lane & 7)) * 8;
      if constexpr (DT == 0) {
        s16x8 af[4], bg[3];
#pragma unroll
        for (int m = 0; m < 4; ++m)
          af[m] = *(const s16x8*)&As[cb][(wr + m*16 + (lane & 15))*64 + sw];
#pragma unroll
        for (int n = 0; n < 3; ++n)
          bg[n] = *(const s16x8*)&Bs[cb][(wc + n*16 + (lane & 15))*64 + sw];
#pragma unroll
        for (int m = 0; m < 4; ++m)
#pragma unroll
          for (int n = 0; n < 3; ++n)
            acc[m][n] = __builtin_amdgcn_mfma_f32_16x16x32_bf16(af[m], bg[n], acc[m][n], 0, 0, 0);
      } else {
        f16x8 af[4], bg[3];
#pragma unroll
        for (int m = 0; m < 4; ++m)
          af[m] = *(const f16x8*)&As[cb][(wr + m*16 + (lane & 15))*64 + sw];
#pragma unroll
        for (int n = 0; n < 3; ++n)
          bg[n] = *(const f16x8*)&Bs[cb][(wc + n*16 + (lane & 15))*64 + sw];
#pragma unroll
        for (int m = 0; m < 4; ++m)
#pragma unroll
          for (int n = 0; n < 3; ++n)
            acc[m][n] = __builtin_amdgcn_mfma_f32_16x16x32_f16(af[m], bg[n], acc[m][n], 0, 0, 0);
      }
    }
    __builtin_amdgcn_sched_barrier(0);
    __builtin_amdgcn_s_barrier();
  }
#pragma unroll
  for (int m = 0; m < 4; ++m) {
    const long r0 = m0 + wr + m*16 + (lane >> 4)*4;
#pragma unroll
    for (int n = 0; n < 3; ++n) {
      const long c = n0 + wc + n*16 + (lane & 15);
#pragma unroll
      for (int j = 0; j < 4; ++j) {
        const float val = acc[m][n][j];
        if constexpr (EPI == 0) {
          ((float*)Cv)[(r0 + j) * (long)N + c] = val;
        } else if constexpr (EPI == 1) {
          const float tg = val + bias[c];
          ((u16*)Cv)[(r0 + j) * (long)N + c] = f2b(0.5f * tg * (1.0f + erff(tg * 0.70710678118654752440f)));
        } else if constexpr (EPI == 2) {
          ((u16*)Cv)[(r0 + j) * (long)N + c] = f2b(val);
        } else {
          ((u16*)Cv)[(r0 + j) * (long)N + c] = f2b(val + bias[c]);
        }
      }
    }
  }
  (void)M;
}

// ---------------- weight packing (LDS-tiled, coalesced; batched over layers via gridDim.z) ----------------
__global__ __launch_bounds__(256) void k_transpose_qkvo(const float* __restrict__ Wq, const float* __restrict__ Wk,
                                                        const float* __restrict__ Wv, const float* __restrict__ Wo,
                                                        u16* __restrict__ wqkvT, u16* __restrict__ woT)
{
  __shared__ float tile[64][65];
  const int z = blockIdx.z, L = z >> 2, t = z & 3;
  const float* src = ((t == 0) ? Wq : (t == 1) ? Wk : (t == 2) ? Wv : Wo) + (size_t)L*768*768;
  u16* dst = (t < 3) ? (wqkvT + (size_t)L*2304*768 + (size_t)t*768*768) : (woT + (size_t)L*768*768);
  const int kb = blockIdx.x * 64, nb = blockIdx.y * 64;
  const int tx = threadIdx.x & 63, ty = threadIdx.x >> 6;
#pragma unroll
  for (int r = ty; r < 64; r += 4)
    tile[r][tx] = src[(long)(kb + r) * 768 + nb + tx];
  __syncthreads();
#pragma unroll
  for (int r = ty; r < 64; r += 4)
    dst[(long)(nb + r) * 768 + kb + tx] = f2b(tile[tx][r]);
}

__global__ __launch_bounds__(256) void k_transpose_w1(const float* __restrict__ W1, u16* __restrict__ w1T)
{
  __shared__ float tile[64][65];
  const int L = blockIdx.z;
  const float* src = W1 + (size_t)L*768*3072;
  u16* dst = w1T + (size_t)L*3072*768;
  const int kb = blockIdx.x * 64, nb = blockIdx.y * 64;
  const int tx = threadIdx.x & 63, ty = threadIdx.x >> 6;
#pragma unroll
  for (int r = ty; r < 64; r += 4)
    tile[r][tx] = src[(long)(kb + r) * 3072 + nb + tx];
  __syncthreads();
#pragma unroll
  for (int r = ty; r < 64; r += 4)
    dst[(long)(nb + r) * 768 + kb + tx] = f2b(tile[tx][r]);
}

__global__ __launch_bounds__(256) void k_transpose_w2(const float* __restrict__ W2, u16* __restrict__ w2T)
{
  __shared__ float tile[64][65];
  const int L = blockIdx.z;
  const float* src = W2 + (size_t)L*3072*768;
  u16* dst = w2T + (size_t)L*768*3072;
  const int kb = blockIdx.x * 64, nb = blockIdx.y * 64;
  const int tx = threadIdx.x & 63, ty = threadIdx.x >> 6;
#pragma unroll
  for (int r = ty; r < 64; r += 4)
    tile[r][tx] = src[(long)(kb + r) * 768 + nb + tx];
  __syncthreads();
#pragma unroll
  for (int r = ty; r < 64; r += 4)
    dst[(long)(nb + r) * 3072 + kb + tx] = f2b(tile[tx][r]);
}

// conv_w [3][768][768] (t,d,o) -> w3t[o][t*2304 + d*3 + p], p: {hi,hi,lo}
__global__ __launch_bounds__(256) void k_pack_w3t_tile(const float* __restrict__ conv_w, u16* __restrict__ w3t)
{
  __shared__ float tile[64][65];
  const int t = blockIdx.z;
  const int db = blockIdx.x * 64, ob = blockIdx.y * 64;
  const int tx = threadIdx.x & 63, ty = threadIdx.x >> 6;
#pragma unroll
  for (int r = ty; r < 64; r += 4)
    tile[r][tx] = conv_w[((long)t * 768 + db + r) * 768 + ob + tx];
  __syncthreads();
#pragma unroll
  for (int r = ty; r < 64; r += 4) {
    const float wv = tile[tx][r];                 // d = db+tx, o = ob+r
    const _Float16 hi = (_Float16)wv;
    const u16 uh = h_bits(hi);
    const u16 ul = h_bits((_Float16)(wv - (float)hi));
    u16* p = &w3t[(long)(ob + r) * KC + t * 2304 + (db + tx) * 3];
    p[0] = uh; p[1] = uh; p[2] = ul;
  }
}

__global__ void k_pack_qkvbias(const float* __restrict__ bq, const float* __restrict__ bk,
                               const float* __restrict__ bv, float* __restrict__ dst)
{
  const int idx = blockIdx.x*256 + threadIdx.x;
  if (idx >= 4*2304) return;
  const int L = idx / 2304, c = idx % 2304;
  const float* src = (c < 768) ? bq : (c < 1536 ? bk : bv);
  dst[idx] = src[L*768 + (c % 768)];
}

// ---------------- stage 1 ----------------
__global__ void k_build_chunks(const int* __restrict__ doc_ids, int* __restrict__ chunks, int* __restrict__ valid)
{
  const int bp = blockIdx.x;                  // 2560
  const int b = bp / NP, p = bp % NP;
  const int e = threadIdx.x;                  // 64
  const int j = p*50 + e;
  int id = 0;
  const int di = j - 6;                       // doc index (d_ids = doc_ids[:,1:], pad OVERLAP=7 left)
  if (j >= 7 && di < 4000) id = doc_ids[b*4000 + di];
  chunks[bp*64 + e] = id;
  const unsigned long long bal = __ballot(e >= 7 && e < 57 && id != 0);
  if (e == 0) valid[bp] = (bal != 0ULL) ? 1 : 0;
}

// embed + LN -> split fp16 {hi, lo, hi} source  A3[seg_local][66][768*3]
__global__ __launch_bounds__(256) void k_emb_conv(const int* __restrict__ chunks,
    const int* __restrict__ query_ids, const float* __restrict__ word_emb,
    const float* __restrict__ pos_emb, const float* __restrict__ g,
    const float* __restrict__ bb, u16* __restrict__ A3, int seg0, int nT)
{
  const int Tl = blockIdx.x*4 + (threadIdx.x >> 6);
  if (Tl >= nT) return;
  const int lane = threadIdx.x & 63;
  const int seg = seg0 + Tl / 66, tok = Tl % 66;
  int id = -1;
  if (seg < NSEGC) { if (tok < 64) id = chunks[seg*64 + tok]; }
  else             { if (tok < LQ) id = query_ids[(seg - NSEGC)*LQ + tok]; }
  const long ob = (long)Tl * 2304;
  if (id < 0) {
#pragma unroll
    for (int j = 0; j < 12; ++j) {
      const int d = lane + 64*j;
      A3[ob + d*3 + 0] = 0; A3[ob + d*3 + 1] = 0; A3[ob + d*3 + 2] = 0;
    }
    return;
  }
  float v[12]; float s = 0.f;
#pragma unroll
  for (int j = 0; j < 12; ++j) {
    const int d = lane + 64*j;
    v[j] = word_emb[(long)id*DD + d] + pos_emb[(long)tok*DD + d];
    s += v[j];
  }
  s = wsum(s);
  const float mean = s * (1.f/768.f);
  float q = 0.f;
#pragma unroll
  for (int j = 0; j < 12; ++j) { const float t = v[j] - mean; q += t*t; }
  q = wsum(q);
  const float rstd = 1.f / sqrtf(q * (1.f/768.f) + 1e-12f);
#pragma unroll
  for (int j = 0; j < 12; ++j) {
    const int d = lane + 64*j;
    const float y = (v[j] - mean) * rstd * g[d] + bb[d];
    const _Float16 hi = (_Float16)y;
    const _Float16 lo = (_Float16)(y - (float)hi);
    const u16 uh = h_bits(hi);
    A3[ob + d*3 + 0] = uh;
    A3[ob + d*3 + 1] = h_bits(lo);
    A3[ob + d*3 + 2] = uh;
  }
}

__global__ __launch_bounds__(256) void k_conv_epi(float* __restrict__ Y, const float* __restrict__ cb)
{
  const int r = blockIdx.x*4 + (threadIdx.x >> 6);
  const int lane = threadIdx.x & 63;
  const long base = (long)r * DD;
  float v[12]; float ss = 0.f;
#pragma unroll
  for (int j = 0; j < 12; ++j) {
    const int d = lane + 64*j;
    float t = Y[base + d] + cb[d];
    t = fmaxf(t, 0.f);
    v[j] = t; ss += t*t;
  }
  ss = wsum(ss);
  const float sc = 1.f / fmaxf(sqrtf(ss), 1e-12f);
#pragma unroll
  for (int j = 0; j < 12; ++j) Y[base + lane + 64*j] = v[j]*sc;
}

// cos-pool, single-read: all 30 Q-rows in LDS (92KB, 512 thr, 1 block/CU = 8 waves/CU);
// relu'd row cached in dv[12] REGISTERS, two q-groups of acc[15] processed sequentially.
// (R15 lesson / rule #20: acc[30] + e-loop unroll spilled to scratch -> 6x over-fetch.
//  unroll-1 guards on the e- and g-loops keep peak live regs ~45.)
// Same per-(q,e) FMA order and rn as the 2-pass version -> bit-identical samp.
__global__ __launch_bounds__(512) void k_cos_pool(const float* __restrict__ Yraw,
    const float* __restrict__ cb, const float* __restrict__ qctx,
    const int* __restrict__ chunks, const int* __restrict__ valid,
    const int* __restrict__ query_mask, const float* __restrict__ alpha,
    const float* __restrict__ binw_w, const float* __restrict__ binw_b,
    float* __restrict__ samp, int seg0)
{
  __shared__ float Qs[30*768];     // 92,160 B
  __shared__ float cosm[30*64];
  __shared__ float cbs[768];
  __shared__ float maskf[64];
  __shared__ float qmw[32];
  __shared__ float red[8];
  const int bp = seg0 + blockIdx.x;
  const int b = bp / NP;
  const int tid = threadIdx.x, lane = tid & 63, w = tid >> 6;   // w 0..7
  if (tid < 64) maskf[tid] = (chunks[bp*64 + tid] != 0) ? 1.f : 0.f;
  if (tid < LQ) qmw[tid] = (float)query_mask[b*LQ + tid];
  for (int idx = tid; idx < 768; idx += 512) cbs[idx] = cb[idx];
  const long dbase = (long)blockIdx.x * 64 * DD;
  const long qrow0 = (long)b * 64;
  for (int idx = tid; idx < 30*768; idx += 512)
    Qs[idx] = qctx[(qrow0 + idx/768)*DD + (idx % 768)];
  __syncthreads();
#pragma unroll 1
  for (int e = w; e < 64; e += 8) {
    float dv[12];
    float nrm = 0.f;
#pragma unroll
    for (int j = 0; j < 12; ++j) {
      const int d = lane + 64*j;
      dv[j] = fmaxf(Yraw[dbase + (long)e*DD + d] + cbs[d], 0.f);
      nrm += dv[j]*dv[j];
    }
    nrm = wsum(nrm);
    const float rn = 1.f / fmaxf(sqrtf(nrm), 1e-12f);
#pragma unroll 1
    for (int g = 0; g < 2; ++g) {
      float acc[15];
#pragma unroll
      for (int q = 0; q < 15; ++q) acc[q] = 0.f;
#pragma unroll
      for (int j = 0; j < 12; ++j) {
        const int d = lane + 64*j;
#pragma unroll
        for (int q = 0; q < 15; ++q)
          acc[q] += dv[j] * Qs[(g*15 + q)*768 + d];
      }
#pragma unroll
      for (int q = 0; q < 15; ++q) {
        const float sv = wsum(acc[q]);
        if (lane == q) cosm[(g*15 + q)*64 + e] = sv * rn;
      }
    }
  }
  __syncthreads();
  float part = 0.f;
  for (int pr = tid; pr < 330; pr += 512) {
    const int q = pr / 11, mi = pr % 11;
    const float mu = MU_C[mi];
    float ks = 0.f;
    for (int e = 0; e < 64; ++e) {
      const float c = cosm[q*64 + e] - mu;
      ks += expf(-c*c*50.f) * maskf[e];
    }
    part += logf(fmaxf(ks * alpha[mi], 1e-4f)) * qmw[q] * binw_w[mi];
  }
  part = wsum(part);
  if (lane == 0) red[w] = part;
  __syncthreads();
  if (tid == 0) {
    float s = binw_b[0];
#pragma unroll
    for (int i = 0; i < 8; ++i) s += red[i];
    samp[bp] = (valid[bp] != 0 && s != 0.f) ? s : -9000.0f;
  }
}

__global__ void k_top8(const float* __restrict__ samp, const int* __restrict__ valid,
                       int* __restrict__ topidx, int* __restrict__ selv)
{
  const int b = blockIdx.x;
  const int l = threadIdx.x;  // 64
  float v1 = samp[b*NP + l];
  float v2 = (l < NP - 64) ? samp[b*NP + 64 + l] : -3e38f;
  for (int r = 0; r < 8; ++r) {
    float cv; int ci;
    if (v2 > v1) { cv = v2; ci = l + 64; } else { cv = v1; ci = l; }
#pragma unroll
    for (int o = 32; o; o >>= 1) {
      const float ov = __shfl_xor(cv, o);
      const int   oi = __shfl_xor(ci, o);
      if (ov > cv || (ov == cv && oi < ci)) { cv = ov; ci = oi; }
    }
    if (l == 0) { topidx[b*8 + r] = ci; selv[b*8 + r] = valid[b*NP + ci]; }
    if (ci == l)      v1 = -3e38f;
    if (ci == l + 64) v2 = -3e38f;
  }
}

// ---------------- stage 2: BERT ----------------
__global__ __launch_bounds__(256) void k_bert_emb(const int* __restrict__ chunks,
    const int* __restrict__ query_ids, const int* __restrict__ query_mask,
    const int* __restrict__ topidx, const float* __restrict__ word_emb,
    const float* __restrict__ pos_emb, const float* __restrict__ g, const float* __restrict__ bb,
    float* __restrict__ xf, u16* __restrict__ xb, int* __restrict__ am, int n0)
{
  const int Tl = blockIdx.x*4 + (threadIdx.x >> 6);     // slice-local token
  const int lane = threadIdx.x & 63;
  const int nl = Tl / LB, l = Tl % LB;
  const int n = n0 + nl;
  const int b = n >> 3, jj = n & 7;
  int id, amv;
  if (l < LQ) { id = query_ids[b*LQ + l]; amv = (query_mask[b*LQ + l] != 0) ? 1 : 0; }
  else { const int p = topidx[b*8 + jj]; id = chunks[(b*NP + p)*64 + (l - LQ)]; amv = (id != 0) ? 1 : 0; }
  if (lane == 0) am[n*LB + l] = amv;
  const long ob = (long)Tl * DD;
  float v[12]; float s = 0.f;
#pragma unroll
  for (int j = 0; j < 12; ++j) {
    const int d = lane + 64*j;
    v[j] = word_emb[(long)id*DD + d] + pos_emb[(long)l*DD + d];
    s += v[j];
  }
  s = wsum(s);
  const float mean = s * (1.f/768.f);
  float q = 0.f;
#pragma unroll
  for (int j = 0; j < 12; ++j) { const float t = v[j] - mean; q += t*t; }
  q = wsum(q);
  const float rstd = 1.f / sqrtf(q*(1.f/768.f) + 1e-12f);
#pragma unroll
  for (int j = 0; j < 12; ++j) {
    const int d = lane + 64*j;
    const float y = (v[j] - mean)*rstd*g[d] + bb[d];
    xf[ob + d] = y;
    xb[ob + d] = f2b(y);
  }
}

// MFMA attention: one block = (slice-local seq, head). 6 waves, wave w owns rows [w*16, w*16+16).
__global__ __launch_bounds__(384) void k_attn_mfma(const u16* __restrict__ qkvb,
    const int* __restrict__ am, u16* __restrict__ ctxb, int n0)
{
  __shared__ __align__(16) u16 Kb[96*72];
  __shared__ __align__(16) u16 Vt[64*104];
  __shared__ __align__(16) u16 Pl[6*16*104];
  __shared__ float maskb[96];
  const int nb = blockIdx.x;
  const int nl = nb / 12, h = nb % 12;
  const int tid = threadIdx.x, lane = tid & 63, w = tid >> 6;
  const int hoff = h * 64;
  const long rowbase = (long)nl * LB;

  for (int idx = tid; idx < 96*8; idx += 384) {
    const int l = idx >> 3, seg = idx & 7;
    s16x8 z = {};
    if (l < LB) z = *(const s16x8*)&qkvb[(rowbase + l)*2304 + 768 + hoff + seg*8];
    *(s16x8*)&Kb[l*72 + seg*8] = z;
  }
  for (int idx = tid; idx < 96*64; idx += 384) {
    const int j = idx >> 6, d = idx & 63;
    Vt[d*104 + j] = (j < LB) ? qkvb[(rowbase + j)*2304 + 1536 + hoff + d] : (u16)0;
  }
  if (tid < 96) maskb[tid] = (tid < LB && am[(n0 + nl)*LB + tid] != 0) ? 1.f : 0.f;
  __syncthreads();

  const int rt = w;
  s16x8 qf0, qf1;
  {
    int r = rt*16 + (lane & 15); if (r > LB-1) r = LB-1;
    const long qbase = (rowbase + r)*2304 + hoff + (lane >> 4)*8;
    qf0 = *(const s16x8*)&qkvb[qbase];
    qf1 = *(const s16x8*)&qkvb[qbase + 32];
  }
  f32x4 sa[6];
#pragma unroll
  for (int ct = 0; ct < 6; ++ct) {
    sa[ct] = f32x4{0.f,0.f,0.f,0.f};
    const int krow = ct*16 + (lane & 15);
    const s16x8 kf0 = *(const s16x8*)&Kb[krow*72 + (lane >> 4)*8];
    const s16x8 kf1 = *(const s16x8*)&Kb[krow*72 + 32 + (lane >> 4)*8];
    sa[ct] = __builtin_amdgcn_mfma_f32_16x16x32_bf16(qf0, kf0, sa[ct], 0, 0, 0);
    sa[ct] = __builtin_amdgcn_mfma_f32_16x16x32_bf16(qf1, kf1, sa[ct], 0, 0, 0);
  }
  float sv[6][4];
#pragma unroll
  for (int ct = 0; ct < 6; ++ct) {
    const int col = ct*16 + (lane & 15);
    const float mk = maskb[col];
#pragma unroll
    for (int j = 0; j < 4; ++j)
      sv[ct][j] = (mk != 0.f) ? sa[ct][j]*0.125f : -1.0e30f;
  }
  float mx[4], sm[4];
#pragma unroll
  for (int j = 0; j < 4; ++j) {
    float v = sv[0][j];
#pragma unroll
    for (int ct = 1; ct < 6; ++ct) v = fmaxf(v, sv[ct][j]);
#pragma unroll
    for (int o = 1; o < 16; o <<= 1) v = fmaxf(v, __shfl_xor(v, o));
    mx[j] = v;
  }
#pragma unroll
  for (int j = 0; j < 4; ++j) {
    float s = 0.f;
#pragma unroll
    for (int ct = 0; ct < 6; ++ct) { const float p = expf(sv[ct][j] - mx[j]); sv[ct][j] = p; s += p; }
#pragma unroll
    for (int o = 1; o < 16; o <<= 1) s += __shfl_xor(s, o);
    sm[j] = 1.f / s;
  }
  u16* Pw = &Pl[w*16*104];
#pragma unroll
  for (int ct = 0; ct < 6; ++ct)
#pragma unroll
    for (int j = 0; j < 4; ++j)
      Pw[((lane >> 4)*4 + j)*104 + ct*16 + (lane & 15)] = f2b(sv[ct][j]*sm[j]);
  asm volatile("s_waitcnt lgkmcnt(0)" ::: "memory");
  f32x4 oa[4];
#pragma unroll
  for (int nt = 0; nt < 4; ++nt) oa[nt] = f32x4{0.f,0.f,0.f,0.f};
#pragma unroll
  for (int ks = 0; ks < 3; ++ks) {
    const s16x8 pf = *(const s16x8*)&Pw[(lane & 15)*104 + ks*32 + (lane >> 4)*8];
#pragma unroll
    for (int nt = 0; nt < 4; ++nt) {
      const s16x8 vf = *(const s16x8*)&Vt[(nt*16 + (lane & 15))*104 + ks*32 + (lane >> 4)*8];
      oa[nt] = __builtin_amdgcn_mfma_f32_16x16x32_bf16(pf, vf, oa[nt], 0, 0, 0);
    }
  }
#pragma unroll
  for (int nt = 0; nt < 4; ++nt)
#pragma unroll
    for (int j = 0; j < 4; ++j) {
      const int r = rt*16 + (lane >> 4)*4 + j;
      if (r < LB)
        ctxb[(rowbase + r)*768 + hoff + nt*16 + (lane & 15)] = f2b(oa[nt][j]);
    }
}

// LN over resid(fp32) + gout(bf16) + bias; writes fp32 + bf16 copies.
__global__ __launch_bounds__(256) void k_ln(const float* __restrict__ resid,
    const u16* __restrict__ gout, const float* __restrict__ bias,
    const float* __restrict__ g, const float* __restrict__ bb,
    float* __restrict__ of, u16* __restrict__ ob)
{
  const int r = blockIdx.x*4 + (threadIdx.x >> 6);
  const int lane = threadIdx.x & 63;
  const long base = (long)r * DD;
  float v[12]; float s = 0.f;
#pragma unroll
  for (int j = 0; j < 12; ++j) {
    const int d = lane + 64*j;
    v[j] = resid[base + d] + b2f(gout[base + d]) + bias[d];
    s += v[j];
  }
  s = wsum(s);
  const float mean = s * (1.f/768.f);
  float q = 0.f;
#pragma unroll
  for (int j = 0; j < 12; ++j) { const float t = v[j] - mean; q += t*t; }
  q = wsum(q);
  const float rstd = 1.f / sqrtf(q*(1.f/768.f) + 1e-12f);
#pragma unroll
  for (int j = 0; j < 12; ++j) {
    const int d = lane + 64*j;
    const float y = (v[j] - mean)*rstd*g[d] + bb[d];
    of[base + d] = y;
    ob[base + d] = f2b(y);
  }
}

__global__ void k_cls(const float* __restrict__ xf, const float* __restrict__ cls_w,
                      const float* __restrict__ cls_b, float* __restrict__ bscore, int n0)
{
  const int nl = blockIdx.x*4 + (threadIdx.x >> 6);
  const int lane = threadIdx.x & 63;
  const long base = (long)nl * LB * DD;
  float s = 0.f;
#pragma unroll
  for (int j = 0; j < 12; ++j) { const int d = lane + 64*j; s += xf[base + d] * cls_w[d]; }
  s = wsum(s);
  if (lane == 0) bscore[n0 + nl] = s + cls_b[0];
}

__global__ void k_final(const float* __restrict__ bscore, const int* __restrict__ selv,
                        const float* __restrict__ topk_w, float* __restrict__ out)
{
  const int b = threadIdx.x;
  if (b >= NBAT) return;
  float t0 = -3e38f, t1 = -3e38f, t2 = -3e38f;
  for (int j = 0; j < 8; ++j) {
    const float bs = bscore[b*8 + j];
    const float v = (selv[b*8 + j] != 0 && bs != 0.0f) ? bs : -9000.0f;
    if (v > t0)      { t2 = t1; t1 = t0; t0 = v; }
    else if (v > t1) { t2 = t1; t1 = v; }
    else if (v > t2) { t2 = v; }
  }
  t0 = (t0 <= -8900.0f) ? 0.0f : t0;
  t1 = (t1 <= -8900.0f) ? 0.0f : t1;
  t2 = (t2 <= -8900.0f) ? 0.0f : t2;
  out[b] = t0*topk_w[0] + t1*topk_w[1] + t2*topk_w[2];
}

extern "C" void kernel_launch(void* const* d_in, const int* in_sizes, int n_in,
                              void* d_out, int out_size, void* d_ws, size_t ws_size,
                              hipStream_t stream)
{
  const int*   query_ids  = (const int*)d_in[0];
  const int*   query_mask = (const int*)d_in[1];
  const int*   doc_ids    = (const int*)d_in[2];
  const float* word_emb   = (const float*)d_in[3];
  const float* pos_emb    = (const float*)d_in[4];
  const float* emb_ln_g   = (const float*)d_in[5];
  const float* emb_ln_b   = (const float*)d_in[6];
  const float* conv_w     = (const float*)d_in[7];
  const float* conv_b     = (const float*)d_in[8];
  const float* kernel_alpha = (const float*)d_in[9];
  const float* binw_w     = (const float*)d_in[10];
  const float* binw_b     = (const float*)d_in[11];
  const float* cls_w      = (const float*)d_in[12];
  const float* cls_b      = (const float*)d_in[13];
  const float* topk_w     = (const float*)d_in[14];
  const float* Wq  = (const float*)d_in[15];
  const float* bq  = (const float*)d_in[16];
  const float* Wk  = (const float*)d_in[17];
  const float* bk  = (const float*)d_in[18];
  const float* Wv  = (const float*)d_in[19];
  const float* bv  = (const float*)d_in[20];
  const float* Wo  = (const float*)d_in[21];
  const float* bo  = (const float*)d_in[22];
  const float* ln1_g = (const float*)d_in[23];
  const float* ln1_b = (const float*)d_in[24];
  const float* W1  = (const float*)d_in[25];
  const float* bf1 = (const float*)d_in[26];
  const float* W2  = (const float*)d_in[27];
  const float* bf2 = (const float*)d_in[28];
  const float* ln2_g = (const float*)d_in[29];
  const float* ln2_b = (const float*)d_in[30];
  (void)in_sizes; (void)n_in; (void)out_size;

  char* ws = (char*)d_ws;
  size_t o = 0;
  auto take = [&](size_t bytes) { char* p = ws + o; o += bytes; return p; };
  int*   chunks = (int*)take(655360);
  int*   valid  = (int*)take(10240);
  float* samp   = (float*)take(10240);
  int*   topidx = (int*)take(1024);
  int*   selv   = (int*)take(1024);
  int*   am     = (int*)take(96256);
  float* bscore = (float*)take(1024);
  float* qctx   = (float*)take(6291456);
  float* qkvbias= (float*)take(36864);
  u16* w3t   = (u16*)take(10616832UL);
  u16* wqkvT = (u16*)take(14155776UL);
  u16* woT   = (u16*)take(4718592UL);
  u16* w1T   = (u16*)take(18874368UL);
  u16* w2T   = (u16*)take(18874368UL);
  const size_t persist = o;

  // ---- adaptive BERT slicing by ws_size (BSL sequences per slice) ----
  int BSL_ = 64;
  if (ws_size >= persist + (size_t)(256*LB) * 21504UL)      BSL_ = 256;
  else if (ws_size >= persist + (size_t)(128*LB) * 21504UL) BSL_ = 128;
  const int NSL2_ = 256 / BSL_;
  const long M2 = (long)BSL_ * LB;

  // ---- adaptive stage-1 slicing (CSL chunk segments per slice) ----
  // per-seg bytes = 66*2304*2 (A3) + 64*768*4 (Ys) = 500,736
  int CSL_ = 256;
  if (ws_size >= persist + 512UL * 500736UL) CSL_ = 512;
  const int NSL1_ = NSEGC / CSL_;
  const int MSL1_ = CSL_ * 64;

  char* U = ws + persist;
  // stage-1 views
  u16*   A3s = (u16*)U;                                  // CSL_*66*2304*2
  float* Ys  = (float*)(U + (size_t)CSL_ * 304128UL);    // CSL_*64*768*4 (raw conv out; epi fused in cos_pool)
  // BERT views
  u16*   qkvb   = (u16*)U;                               // M2*4608
  u16*   attn_o = (u16*)U;                               // bf16 gout; aliases dead qkvb
  float* xf  = (float*)(U + (size_t)M2*4608UL);          // M2*3072
  float* x1f = (float*)(U + (size_t)M2*7680UL);          // M2*3072
  u16*   xb  = (u16*)(U + (size_t)M2*10752UL);           // M2*1536
  u16*   x1b = (u16*)(U + (size_t)M2*12288UL);           // M2*1536
  u16*   ctxb= (u16*)(U + (size_t)M2*13824UL);           // M2*1536
  u16*   hb  = (u16*)(U + (size_t)M2*15360UL);           // M2*6144 -> end M2*21504

  // ---- weight packing (tiled, coalesced; batched over layers) ----
  k_pack_w3t_tile<<<dim3(12, 12, 3), 256, 0, stream>>>(conv_w, w3t);
  k_pack_qkvbias<<<36, 256, 0, stream>>>(bq, bk, bv, qkvbias);
  k_transpose_qkvo<<<dim3(12,12,16), 256, 0, stream>>>(Wq, Wk, Wv, Wo, wqkvT, woT);
  k_transpose_w1<<<dim3(12,48,4), 256, 0, stream>>>(W1, w1T);
  k_transpose_w2<<<dim3(48,12,4), 256, 0, stream>>>(W2, w2T);

  // ---- stage 1: chunk scoring ----
  k_build_chunks<<<NSEGC, 64, 0, stream>>>(doc_ids, chunks, valid);
  k_emb_conv<<<(NBAT*66)/4, 256, 0, stream>>>(chunks, query_ids, word_emb, pos_emb, emb_ln_g, emb_ln_b,
                                              A3s, NSEGC, NBAT*66);
  gemm_mid<1,1,0><<<(NBAT*64/128)*(DD/192), 512, 0, stream>>>(A3s, w3t, qctx, nullptr, NBAT*64, DD, KC);
  k_conv_epi<<<(NBAT*64)/4, 256, 0, stream>>>(qctx, conv_b);
  for (int s = 0; s < NSL1_; ++s) {
    const int seg0 = s * CSL_;
    k_emb_conv<<<(CSL_*66+3)/4, 256, 0, stream>>>(chunks, query_ids, word_emb, pos_emb, emb_ln_g, emb_ln_b,
                                                  A3s, seg0, CSL_*66);
    gemm_mid<1,1,0><<<(MSL1_/128)*(DD/192), 512, 0, stream>>>(A3s, w3t, Ys, nullptr, MSL1_, DD, KC);
    k_cos_pool<<<CSL_, 512, 0, stream>>>(Ys, conv_b, qctx, chunks, valid, query_mask, kernel_alpha,
                                         binw_w, binw_b, samp, seg0);
  }
  k_top8<<<NBAT, 64, 0, stream>>>(samp, valid, topidx, selv);

  // ---- stage 2: BERT rerank (adaptive slices; all GEMMs on gemm_mid) ----
  for (int t = 0; t < NSL2_; ++t) {
    const int n0 = t * BSL_;
    k_bert_emb<<<(int)(M2/4), 256, 0, stream>>>(chunks, query_ids, query_mask, topidx, word_emb, pos_emb,
                                                emb_ln_g, emb_ln_b, xf, xb, am, n0);
    for (int L = 0; L < 4; ++L) {
      gemm_mid<0,0,3><<<(int)((M2/128)*(2304/192)), 512, 0, stream>>>(xb, wqkvT + (size_t)L*2304*768, qkvb, qkvbias + L*2304, (int)M2, 2304, 768);
      k_attn_mfma<<<BSL_*12, 384, 0, stream>>>(qkvb, am, ctxb, n0);
      gemm_mid<0,0,2><<<(int)((M2/128)*(768/192)), 512, 0, stream>>>(ctxb, woT + (size_t)L*768*768, attn_o, nullptr, (int)M2, 768, 768);
      k_ln<<<(int)(M2/4), 256, 0, stream>>>(xf, attn_o, bo + L*768, ln1_g + L*768, ln1_b + L*768, x1f, x1b);
      gemm_mid<0,0,1><<<(int)((M2/128)*(3072/192)), 512, 0, stream>>>(x1b, w1T + (size_t)L*3072*768, hb, bf1 + L*3072, (int)M2, 3072, 768);
      gemm_mid<0,0,2><<<(int)((M2/128)*(768/192)), 512, 0, stream>>>(hb, w2T + (size_t)L*768*3072, attn_o, nullptr, (int)M2, 768, 3072);
      k_ln<<<(int)(M2/4), 256, 0, stream>>>(x1f, attn_o, bf2 + L*768, ln2_g + L*768, ln2_b + L*768, xf, xb);
    }
    k_cls<<<BSL_/4, 256, 0, stream>>>(xf, cls_w, cls_b, bscore, n0);
  }
  k_final<<<1, 64, 0, stream>>>(bscore, selv, topk_w, (float*)d_out);
}

// Round 18
// 5361.243 us; speedup vs baseline: 1.0302x; 1.0302x over previous
//
#include <hip/hip_runtime.h>
#include <hip/hip_bf16.h>
#include <cstring>
#include <cmath>

#define NBAT 32
#define LQ 30
#define NP 80
#define NSEGC 2560   // NBAT*NP chunk segments
#define DD 768
#define KC 6912      // 2304 * 3 precision parts
#define LB 94
#define FF 3072

typedef unsigned short u16;
typedef __attribute__((__ext_vector_type__(4))) float f32x4;
typedef __attribute__((__ext_vector_type__(8))) short s16x8;
typedef __attribute__((__ext_vector_type__(8))) _Float16 f16x8;

__constant__ float MU_C[11] = {1.0f,0.9f,0.7f,0.5f,0.3f,0.1f,-0.1f,-0.3f,-0.5f,-0.7f,-0.9f};

__device__ __forceinline__ float wsum(float v) {
#pragma unroll
  for (int o = 32; o; o >>= 1) v += __shfl_xor(v, o);
  return v;
}
__device__ __forceinline__ u16 f2b(float f) {
  __hip_bfloat16 h = __float2bfloat16(f);
  u16 u; __builtin_memcpy(&u, &h, 2); return u;
}
__device__ __forceinline__ float b2f(u16 u) {
  unsigned v = ((unsigned)u) << 16; float f; __builtin_memcpy(&f, &v, 4); return f;
}
__device__ __forceinline__ u16 h_bits(_Float16 h) { u16 u; __builtin_memcpy(&u, &h, 2); return u; }

__device__ __forceinline__ void gll16(const void* g, void* l) {
  __builtin_amdgcn_global_load_lds((const __attribute__((address_space(1))) unsigned*)g,
                                   (__attribute__((address_space(3))) unsigned*)l, 16, 0, 0);
}

// ---------------- mid 128x192 MFMA GEMM, 512 thr (8 waves x 64x48), BK=64, 2-phase dbuf ----------------
// R12-proven geometry: LDS 80KB -> 2 blocks/CU = 16 waves/CU (R13 lesson: 4-wave re-tile halved
// resident waves and lost more TLP than its LDS-read saving bought; wave count is first-order).
// rule-#21 XOR-swizzled LDS, XCD-chunked bijective swizzle, full-tile-ahead prefetch + counted
// vmcnt(5) (R10 lesson: never collapse prefetch distance). Identical per-element K-order.
// AMODE: 0 flat [M][K], 1 conv-im2col over [seg][66][2304]. DT: 0 bf16, 1 f16.
// EPI: 0 fp32; 1 bf16 gelu(acc+bias); 2 bf16 acc; 3 bf16 acc+bias.
template<int AMODE, int DT, int EPI>
__global__ __launch_bounds__(512) void gemm_mid(const u16* __restrict__ A, const u16* __restrict__ BT,
                                                void* __restrict__ Cv, const float* __restrict__ bias,
                                                int M, int N, int K)
{
  __shared__ __align__(16) u16 As[2][128*64];   // 32 KB
  __shared__ __align__(16) u16 Bs[2][192*64];   // 48 KB
  const int tid = threadIdx.x;
  const int lane = tid & 63;
  const int w = tid >> 6;          // 0..7

  const int NBY = N / 192;
  const int nb = gridDim.x;
  const int q8 = nb >> 3, r8 = nb & 7;
  const int xcd = blockIdx.x & 7, slot = blockIdx.x >> 3;
  const int base8 = (xcd < r8) ? xcd*(q8+1) : r8*(q8+1) + (xcd - r8)*q8;
  const int wk = base8 + slot;
  const long m0 = (long)(wk / NBY) * 128;
  const long n0 = (long)(wk % NBY) * 192;

  const int wr = (w >> 2) * 64;    // 0 or 64
  const int wc = (w & 3) * 48;     // 0,48,96,144

  const int lrow = lane >> 3;                  // 0..7
  const int scg  = (lane & 7) ^ lrow;          // inverse-swizzled global k-chunk

  long aoff[2], boff[3];
#pragma unroll
  for (int it = 0; it < 2; ++it) {
    const long ga = m0 + it*64 + w*8 + lrow;
    if (AMODE == 0) aoff[it] = ga * (long)K;
    else            aoff[it] = ((ga >> 6) * 66 + (ga & 63)) * 2304L;
  }
#pragma unroll
  for (int it = 0; it < 3; ++it)
    boff[it] = (long)(n0 + it*64 + w*8 + lrow) * (long)K;

  f32x4 acc[4][3] = {};

  const int T = K >> 6;
  // prologue: stage tile 0 (5 loads/wave)
#pragma unroll
  for (int it = 0; it < 2; ++it)
    gll16(A + aoff[it] + scg*8, &As[0][(it*64 + w*8) * 64]);
#pragma unroll
  for (int it = 0; it < 3; ++it)
    gll16(BT + boff[it] + scg*8, &Bs[0][(it*64 + w*8) * 64]);

  for (int t = 0; t < T; ++t) {
    const int cb = t & 1;
    if (t + 1 < T) {
      const int k1 = (t + 1) << 6;
#pragma unroll
      for (int it = 0; it < 2; ++it)
        gll16(A + aoff[it] + k1 + scg*8, &As[cb ^ 1][(it*64 + w*8) * 64]);
#pragma unroll
      for (int it = 0; it < 3; ++it)
        gll16(BT + boff[it] + k1 + scg*8, &Bs[cb ^ 1][(it*64 + w*8) * 64]);
      asm volatile("s_waitcnt vmcnt(5)" ::: "memory");   // tile-t loads done; 5 newer in flight
    } else {
      asm volatile("s_waitcnt vmcnt(0)" ::: "memory");
    }
    __builtin_amdgcn_s_barrier();
    __builtin_amdgcn_sched_barrier(0);
#pragma unroll
    for (int kk = 0; kk < 2; ++kk) {
      const int cc = kk*4 + (lane >> 4);
      const int sw = (cc ^ (lane & 7)) * 8;
      if constexpr (DT == 0) {
        s16x8 af[4], bg[3];
#pragma unroll
        for (int m = 0; m < 4; ++m)
          af[m] = *(const s16x8*)&As[cb][(wr + m*16 + (lane & 15))*64 + sw];
#pragma unroll
        for (int n = 0; n < 3; ++n)
          bg[n] = *(const s16x8*)&Bs[cb][(wc + n*16 + (lane & 15))*64 + sw];
#pragma unroll
        for (int m = 0; m < 4; ++m)
#pragma unroll
          for (int n = 0; n < 3; ++n)
            acc[m][n] = __builtin_amdgcn_mfma_f32_16x16x32_bf16(af[m], bg[n], acc[m][n], 0, 0, 0);
      } else {
        f16x8 af[4], bg[3];
#pragma unroll
        for (int m = 0; m < 4; ++m)
          af[m] = *(const f16x8*)&As[cb][(wr + m*16 + (lane & 15))*64 + sw];
#pragma unroll
        for (int n = 0; n < 3; ++n)
          bg[n] = *(const f16x8*)&Bs[cb][(wc + n*16 + (lane & 15))*64 + sw];
#pragma unroll
        for (int m = 0; m < 4; ++m)
#pragma unroll
          for (int n = 0; n < 3; ++n)
            acc[m][n] = __builtin_amdgcn_mfma_f32_16x16x32_f16(af[m], bg[n], acc[m][n], 0, 0, 0);
      }
    }
    __builtin_amdgcn_sched_barrier(0);
    __builtin_amdgcn_s_barrier();
  }
#pragma unroll
  for (int m = 0; m < 4; ++m) {
    const long r0 = m0 + wr + m*16 + (lane >> 4)*4;
#pragma unroll
    for (int n = 0; n < 3; ++n) {
      const long c = n0 + wc + n*16 + (lane & 15);
#pragma unroll
      for (int j = 0; j < 4; ++j) {
        const float val = acc[m][n][j];
        if constexpr (EPI == 0) {
          ((float*)Cv)[(r0 + j) * (long)N + c] = val;
        } else if constexpr (EPI == 1) {
          const float tg = val + bias[c];
          ((u16*)Cv)[(r0 + j) * (long)N + c] = f2b(0.5f * tg * (1.0f + erff(tg * 0.70710678118654752440f)));
        } else if constexpr (EPI == 2) {
          ((u16*)Cv)[(r0 + j) * (long)N + c] = f2b(val);
        } else {
          ((u16*)Cv)[(r0 + j) * (long)N + c] = f2b(val + bias[c]);
        }
      }
    }
  }
  (void)M;
}

// ---------------- weight packing (LDS-tiled, coalesced; batched over layers via gridDim.z) ----------------
__global__ __launch_bounds__(256) void k_transpose_qkvo(const float* __restrict__ Wq, const float* __restrict__ Wk,
                                                        const float* __restrict__ Wv, const float* __restrict__ Wo,
                                                        u16* __restrict__ wqkvT, u16* __restrict__ woT)
{
  __shared__ float tile[64][65];
  const int z = blockIdx.z, L = z >> 2, t = z & 3;
  const float* src = ((t == 0) ? Wq : (t == 1) ? Wk : (t == 2) ? Wv : Wo) + (size_t)L*768*768;
  u16* dst = (t < 3) ? (wqkvT + (size_t)L*2304*768 + (size_t)t*768*768) : (woT + (size_t)L*768*768);
  const int kb = blockIdx.x * 64, nb = blockIdx.y * 64;
  const int tx = threadIdx.x & 63, ty = threadIdx.x >> 6;
#pragma unroll
  for (int r = ty; r < 64; r += 4)
    tile[r][tx] = src[(long)(kb + r) * 768 + nb + tx];
  __syncthreads();
#pragma unroll
  for (int r = ty; r < 64; r += 4)
    dst[(long)(nb + r) * 768 + kb + tx] = f2b(tile[tx][r]);
}

__global__ __launch_bounds__(256) void k_transpose_w1(const float* __restrict__ W1, u16* __restrict__ w1T)
{
  __shared__ float tile[64][65];
  const int L = blockIdx.z;
  const float* src = W1 + (size_t)L*768*3072;
  u16* dst = w1T + (size_t)L*3072*768;
  const int kb = blockIdx.x * 64, nb = blockIdx.y * 64;
  const int tx = threadIdx.x & 63, ty = threadIdx.x >> 6;
#pragma unroll
  for (int r = ty; r < 64; r += 4)
    tile[r][tx] = src[(long)(kb + r) * 3072 + nb + tx];
  __syncthreads();
#pragma unroll
  for (int r = ty; r < 64; r += 4)
    dst[(long)(nb + r) * 768 + kb + tx] = f2b(tile[tx][r]);
}

__global__ __launch_bounds__(256) void k_transpose_w2(const float* __restrict__ W2, u16* __restrict__ w2T)
{
  __shared__ float tile[64][65];
  const int L = blockIdx.z;
  const float* src = W2 + (size_t)L*3072*768;
  u16* dst = w2T + (size_t)L*768*3072;
  const int kb = blockIdx.x * 64, nb = blockIdx.y * 64;
  const int tx = threadIdx.x & 63, ty = threadIdx.x >> 6;
#pragma unroll
  for (int r = ty; r < 64; r += 4)
    tile[r][tx] = src[(long)(kb + r) * 768 + nb + tx];
  __syncthreads();
#pragma unroll
  for (int r = ty; r < 64; r += 4)
    dst[(long)(nb + r) * 3072 + kb + tx] = f2b(tile[tx][r]);
}

// conv_w [3][768][768] (t,d,o) -> w3t[o][t*2304 + d*3 + p], p: {hi,hi,lo}
__global__ __launch_bounds__(256) void k_pack_w3t_tile(const float* __restrict__ conv_w, u16* __restrict__ w3t)
{
  __shared__ float tile[64][65];
  const int t = blockIdx.z;
  const int db = blockIdx.x * 64, ob = blockIdx.y * 64;
  const int tx = threadIdx.x & 63, ty = threadIdx.x >> 6;
#pragma unroll
  for (int r = ty; r < 64; r += 4)
    tile[r][tx] = conv_w[((long)t * 768 + db + r) * 768 + ob + tx];
  __syncthreads();
#pragma unroll
  for (int r = ty; r < 64; r += 4) {
    const float wv = tile[tx][r];                 // d = db+tx, o = ob+r
    const _Float16 hi = (_Float16)wv;
    const u16 uh = h_bits(hi);
    const u16 ul = h_bits((_Float16)(wv - (float)hi));
    u16* p = &w3t[(long)(ob + r) * KC + t * 2304 + (db + tx) * 3];
    p[0] = uh; p[1] = uh; p[2] = ul;
  }
}

__global__ void k_pack_qkvbias(const float* __restrict__ bq, const float* __restrict__ bk,
                               const float* __restrict__ bv, float* __restrict__ dst)
{
  const int idx = blockIdx.x*256 + threadIdx.x;
  if (idx >= 4*2304) return;
  const int L = idx / 2304, c = idx % 2304;
  const float* src = (c < 768) ? bq : (c < 1536 ? bk : bv);
  dst[idx] = src[L*768 + (c % 768)];
}

// ---------------- stage 1 ----------------
__global__ void k_build_chunks(const int* __restrict__ doc_ids, int* __restrict__ chunks, int* __restrict__ valid)
{
  const int bp = blockIdx.x;                  // 2560
  const int b = bp / NP, p = bp % NP;
  const int e = threadIdx.x;                  // 64
  const int j = p*50 + e;
  int id = 0;
  const int di = j - 6;                       // doc index (d_ids = doc_ids[:,1:], pad OVERLAP=7 left)
  if (j >= 7 && di < 4000) id = doc_ids[b*4000 + di];
  chunks[bp*64 + e] = id;
  const unsigned long long bal = __ballot(e >= 7 && e < 57 && id != 0);
  if (e == 0) valid[bp] = (bal != 0ULL) ? 1 : 0;
}

// embed + LN -> split fp16 {hi, lo, hi} source  A3[seg_local][66][768*3]
__global__ __launch_bounds__(256) void k_emb_conv(const int* __restrict__ chunks,
    const int* __restrict__ query_ids, const float* __restrict__ word_emb,
    const float* __restrict__ pos_emb, const float* __restrict__ g,
    const float* __restrict__ bb, u16* __restrict__ A3, int seg0, int nT)
{
  const int Tl = blockIdx.x*4 + (threadIdx.x >> 6);
  if (Tl >= nT) return;
  const int lane = threadIdx.x & 63;
  const int seg = seg0 + Tl / 66, tok = Tl % 66;
  int id = -1;
  if (seg < NSEGC) { if (tok < 64) id = chunks[seg*64 + tok]; }
  else             { if (tok < LQ) id = query_ids[(seg - NSEGC)*LQ + tok]; }
  const long ob = (long)Tl * 2304;
  if (id < 0) {
#pragma unroll
    for (int j = 0; j < 12; ++j) {
      const int d = lane + 64*j;
      A3[ob + d*3 + 0] = 0; A3[ob + d*3 + 1] = 0; A3[ob + d*3 + 2] = 0;
    }
    return;
  }
  float v[12]; float s = 0.f;
#pragma unroll
  for (int j = 0; j < 12; ++j) {
    const int d = lane + 64*j;
    v[j] = word_emb[(long)id*DD + d] + pos_emb[(long)tok*DD + d];
    s += v[j];
  }
  s = wsum(s);
  const float mean = s * (1.f/768.f);
  float q = 0.f;
#pragma unroll
  for (int j = 0; j < 12; ++j) { const float t = v[j] - mean; q += t*t; }
  q = wsum(q);
  const float rstd = 1.f / sqrtf(q * (1.f/768.f) + 1e-12f);
#pragma unroll
  for (int j = 0; j < 12; ++j) {
    const int d = lane + 64*j;
    const float y = (v[j] - mean) * rstd * g[d] + bb[d];
    const _Float16 hi = (_Float16)y;
    const _Float16 lo = (_Float16)(y - (float)hi);
    const u16 uh = h_bits(hi);
    A3[ob + d*3 + 0] = uh;
    A3[ob + d*3 + 1] = h_bits(lo);
    A3[ob + d*3 + 2] = uh;
  }
}

__global__ __launch_bounds__(256) void k_conv_epi(float* __restrict__ Y, const float* __restrict__ cb)
{
  const int r = blockIdx.x*4 + (threadIdx.x >> 6);
  const int lane = threadIdx.x & 63;
  const long base = (long)r * DD;
  float v[12]; float ss = 0.f;
#pragma unroll
  for (int j = 0; j < 12; ++j) {
    const int d = lane + 64*j;
    float t = Y[base + d] + cb[d];
    t = fmaxf(t, 0.f);
    v[j] = t; ss += t*t;
  }
  ss = wsum(ss);
  const float sc = 1.f / fmaxf(sqrtf(ss), 1e-12f);
#pragma unroll
  for (int j = 0; j < 12; ++j) Y[base + lane + 64*j] = v[j]*sc;
}

// cos-pool with fused conv epilogue (R14/R16-proven two-pass): dv = relu(Yraw + cb), row-norm in-pass.
// acc[15] per thread, 256 threads, 2 blocks/CU. (R15 lesson: acc[30] spilled; R17 lesson: 92KB-LDS
// single-read variant lost more occupancy/ILP than its L3-served traffic saving was worth.)
__global__ __launch_bounds__(256) void k_cos_pool(const float* __restrict__ Yraw,
    const float* __restrict__ cb, const float* __restrict__ qctx,
    const int* __restrict__ chunks, const int* __restrict__ valid,
    const int* __restrict__ query_mask, const float* __restrict__ alpha,
    const float* __restrict__ binw_w, const float* __restrict__ binw_b,
    float* __restrict__ samp, int seg0)
{
  __shared__ float Qs[15*768];
  __shared__ float cosm[30*64];
  __shared__ float cbs[768];
  __shared__ float normv[64];
  __shared__ float maskf[64];
  __shared__ float qmw[32];
  __shared__ float red[4];
  const int bp = seg0 + blockIdx.x;
  const int b = bp / NP;
  const int tid = threadIdx.x, lane = tid & 63, w = tid >> 6;
  if (tid < 64) maskf[tid] = (chunks[bp*64 + tid] != 0) ? 1.f : 0.f;
  if (tid < LQ) qmw[tid] = (float)query_mask[b*LQ + tid];
  for (int idx = tid; idx < 768; idx += 256) cbs[idx] = cb[idx];
  const long dbase = (long)blockIdx.x * 64 * DD;
  const long qrow0 = (long)b * 64;
  for (int pass = 0; pass < 2; ++pass) {
    const int q0 = pass * 15;
    for (int idx = tid; idx < 15*768; idx += 256)
      Qs[idx] = qctx[(qrow0 + q0 + idx/768)*DD + (idx % 768)];
    __syncthreads();
    for (int e = w; e < 64; e += 4) {
      float acc[15];
#pragma unroll
      for (int q = 0; q < 15; ++q) acc[q] = 0.f;
      float nrm = 0.f;
#pragma unroll
      for (int j = 0; j < 12; ++j) {
        const int d = lane + 64*j;
        const float dv = fmaxf(Yraw[dbase + (long)e*DD + d] + cbs[d], 0.f);
        nrm += dv*dv;
#pragma unroll
        for (int q = 0; q < 15; ++q)
          acc[q] += dv * Qs[q*768 + d];
      }
      float rn;
      if (pass == 0) {
        nrm = wsum(nrm);
        rn = 1.f / fmaxf(sqrtf(nrm), 1e-12f);
        if (lane == 32) normv[e] = rn;
      } else {
        rn = normv[e];
      }
#pragma unroll
      for (int q = 0; q < 15; ++q) {
        const float sv = wsum(acc[q]);
        if (lane == q) cosm[(q0 + q)*64 + e] = sv * rn;
      }
    }
    __syncthreads();   // protect Qs (and normv) before next pass's overwrite
  }
  float part = 0.f;
  for (int pr = tid; pr < 330; pr += 256) {
    const int q = pr / 11, mi = pr % 11;
    const float mu = MU_C[mi];
    float ks = 0.f;
    for (int e = 0; e < 64; ++e) {
      const float c = cosm[q*64 + e] - mu;
      ks += expf(-c*c*50.f) * maskf[e];
    }
    part += logf(fmaxf(ks * alpha[mi], 1e-4f)) * qmw[q] * binw_w[mi];
  }
  part = wsum(part);
  if (lane == 0) red[w] = part;
  __syncthreads();
  if (tid == 0) {
    const float s = red[0] + red[1] + red[2] + red[3] + binw_b[0];
    samp[bp] = (valid[bp] != 0 && s != 0.f) ? s : -9000.0f;
  }
}

__global__ void k_top8(const float* __restrict__ samp, const int* __restrict__ valid,
                       int* __restrict__ topidx, int* __restrict__ selv)
{
  const int b = blockIdx.x;
  const int l = threadIdx.x;  // 64
  float v1 = samp[b*NP + l];
  float v2 = (l < NP - 64) ? samp[b*NP + 64 + l] : -3e38f;
  for (int r = 0; r < 8; ++r) {
    float cv; int ci;
    if (v2 > v1) { cv = v2; ci = l + 64; } else { cv = v1; ci = l; }
#pragma unroll
    for (int o = 32; o; o >>= 1) {
      const float ov = __shfl_xor(cv, o);
      const int   oi = __shfl_xor(ci, o);
      if (ov > cv || (ov == cv && oi < ci)) { cv = ov; ci = oi; }
    }
    if (l == 0) { topidx[b*8 + r] = ci; selv[b*8 + r] = valid[b*NP + ci]; }
    if (ci == l)      v1 = -3e38f;
    if (ci == l + 64) v2 = -3e38f;
  }
}

// ---------------- stage 2: BERT ----------------
__global__ __launch_bounds__(256) void k_bert_emb(const int* __restrict__ chunks,
    const int* __restrict__ query_ids, const int* __restrict__ query_mask,
    const int* __restrict__ topidx, const float* __restrict__ word_emb,
    const float* __restrict__ pos_emb, const float* __restrict__ g, const float* __restrict__ bb,
    float* __restrict__ xf, u16* __restrict__ xb, int* __restrict__ am, int n0)
{
  const int Tl = blockIdx.x*4 + (threadIdx.x >> 6);     // slice-local token
  const int lane = threadIdx.x & 63;
  const int nl = Tl / LB, l = Tl % LB;
  const int n = n0 + nl;
  const int b = n >> 3, jj = n & 7;
  int id, amv;
  if (l < LQ) { id = query_ids[b*LQ + l]; amv = (query_mask[b*LQ + l] != 0) ? 1 : 0; }
  else { const int p = topidx[b*8 + jj]; id = chunks[(b*NP + p)*64 + (l - LQ)]; amv = (id != 0) ? 1 : 0; }
  if (lane == 0) am[n*LB + l] = amv;
  const long ob = (long)Tl * DD;
  float v[12]; float s = 0.f;
#pragma unroll
  for (int j = 0; j < 12; ++j) {
    const int d = lane + 64*j;
    v[j] = word_emb[(long)id*DD + d] + pos_emb[(long)l*DD + d];
    s += v[j];
  }
  s = wsum(s);
  const float mean = s * (1.f/768.f);
  float q = 0.f;
#pragma unroll
  for (int j = 0; j < 12; ++j) { const float t = v[j] - mean; q += t*t; }
  q = wsum(q);
  const float rstd = 1.f / sqrtf(q*(1.f/768.f) + 1e-12f);
#pragma unroll
  for (int j = 0; j < 12; ++j) {
    const int d = lane + 64*j;
    const float y = (v[j] - mean)*rstd*g[d] + bb[d];
    xf[ob + d] = y;
    xb[ob + d] = f2b(y);
  }
}

// MFMA attention: one block = (slice-local seq, head). 6 waves, wave w owns rows [w*16, w*16+16).
__global__ __launch_bounds__(384) void k_attn_mfma(const u16* __restrict__ qkvb,
    const int* __restrict__ am, u16* __restrict__ ctxb, int n0)
{
  __shared__ __align__(16) u16 Kb[96*72];
  __shared__ __align__(16) u16 Vt[64*104];
  __shared__ __align__(16) u16 Pl[6*16*104];
  __shared__ float maskb[96];
  const int nb = blockIdx.x;
  const int nl = nb / 12, h = nb % 12;
  const int tid = threadIdx.x, lane = tid & 63, w = tid >> 6;
  const int hoff = h * 64;
  const long rowbase = (long)nl * LB;

  for (int idx = tid; idx < 96*8; idx += 384) {
    const int l = idx >> 3, seg = idx & 7;
    s16x8 z = {};
    if (l < LB) z = *(const s16x8*)&qkvb[(rowbase + l)*2304 + 768 + hoff + seg*8];
    *(s16x8*)&Kb[l*72 + seg*8] = z;
  }
  for (int idx = tid; idx < 96*64; idx += 384) {
    const int j = idx >> 6, d = idx & 63;
    Vt[d*104 + j] = (j < LB) ? qkvb[(rowbase + j)*2304 + 1536 + hoff + d] : (u16)0;
  }
  if (tid < 96) maskb[tid] = (tid < LB && am[(n0 + nl)*LB + tid] != 0) ? 1.f : 0.f;
  __syncthreads();

  const int rt = w;
  s16x8 qf0, qf1;
  {
    int r = rt*16 + (lane & 15); if (r > LB-1) r = LB-1;
    const long qbase = (rowbase + r)*2304 + hoff + (lane >> 4)*8;
    qf0 = *(const s16x8*)&qkvb[qbase];
    qf1 = *(const s16x8*)&qkvb[qbase + 32];
  }
  f32x4 sa[6];
#pragma unroll
  for (int ct = 0; ct < 6; ++ct) {
    sa[ct] = f32x4{0.f,0.f,0.f,0.f};
    const int krow = ct*16 + (lane & 15);
    const s16x8 kf0 = *(const s16x8*)&Kb[krow*72 + (lane >> 4)*8];
    const s16x8 kf1 = *(const s16x8*)&Kb[krow*72 + 32 + (lane >> 4)*8];
    sa[ct] = __builtin_amdgcn_mfma_f32_16x16x32_bf16(qf0, kf0, sa[ct], 0, 0, 0);
    sa[ct] = __builtin_amdgcn_mfma_f32_16x16x32_bf16(qf1, kf1, sa[ct], 0, 0, 0);
  }
  float sv[6][4];
#pragma unroll
  for (int ct = 0; ct < 6; ++ct) {
    const int col = ct*16 + (lane & 15);
    const float mk = maskb[col];
#pragma unroll
    for (int j = 0; j < 4; ++j)
      sv[ct][j] = (mk != 0.f) ? sa[ct][j]*0.125f : -1.0e30f;
  }
  float mx[4], sm[4];
#pragma unroll
  for (int j = 0; j < 4; ++j) {
    float v = sv[0][j];
#pragma unroll
    for (int ct = 1; ct < 6; ++ct) v = fmaxf(v, sv[ct][j]);
#pragma unroll
    for (int o = 1; o < 16; o <<= 1) v = fmaxf(v, __shfl_xor(v, o));
    mx[j] = v;
  }
#pragma unroll
  for (int j = 0; j < 4; ++j) {
    float s = 0.f;
#pragma unroll
    for (int ct = 0; ct < 6; ++ct) { const float p = expf(sv[ct][j] - mx[j]); sv[ct][j] = p; s += p; }
#pragma unroll
    for (int o = 1; o < 16; o <<= 1) s += __shfl_xor(s, o);
    sm[j] = 1.f / s;
  }
  u16* Pw = &Pl[w*16*104];
#pragma unroll
  for (int ct = 0; ct < 6; ++ct)
#pragma unroll
    for (int j = 0; j < 4; ++j)
      Pw[((lane >> 4)*4 + j)*104 + ct*16 + (lane & 15)] = f2b(sv[ct][j]*sm[j]);
  asm volatile("s_waitcnt lgkmcnt(0)" ::: "memory");
  f32x4 oa[4];
#pragma unroll
  for (int nt = 0; nt < 4; ++nt) oa[nt] = f32x4{0.f,0.f,0.f,0.f};
#pragma unroll
  for (int ks = 0; ks < 3; ++ks) {
    const s16x8 pf = *(const s16x8*)&Pw[(lane & 15)*104 + ks*32 + (lane >> 4)*8];
#pragma unroll
    for (int nt = 0; nt < 4; ++nt) {
      const s16x8 vf = *(const s16x8*)&Vt[(nt*16 + (lane & 15))*104 + ks*32 + (lane >> 4)*8];
      oa[nt] = __builtin_amdgcn_mfma_f32_16x16x32_bf16(pf, vf, oa[nt], 0, 0, 0);
    }
  }
#pragma unroll
  for (int nt = 0; nt < 4; ++nt)
#pragma unroll
    for (int j = 0; j < 4; ++j) {
      const int r = rt*16 + (lane >> 4)*4 + j;
      if (r < LB)
        ctxb[(rowbase + r)*768 + hoff + nt*16 + (lane & 15)] = f2b(oa[nt][j]);
    }
}

// LN over resid(fp32) + gout(bf16) + bias; writes fp32 + bf16 copies.
__global__ __launch_bounds__(256) void k_ln(const float* __restrict__ resid,
    const u16* __restrict__ gout, const float* __restrict__ bias,
    const float* __restrict__ g, const float* __restrict__ bb,
    float* __restrict__ of, u16* __restrict__ ob)
{
  const int r = blockIdx.x*4 + (threadIdx.x >> 6);
  const int lane = threadIdx.x & 63;
  const long base = (long)r * DD;
  float v[12]; float s = 0.f;
#pragma unroll
  for (int j = 0; j < 12; ++j) {
    const int d = lane + 64*j;
    v[j] = resid[base + d] + b2f(gout[base + d]) + bias[d];
    s += v[j];
  }
  s = wsum(s);
  const float mean = s * (1.f/768.f);
  float q = 0.f;
#pragma unroll
  for (int j = 0; j < 12; ++j) { const float t = v[j] - mean; q += t*t; }
  q = wsum(q);
  const float rstd = 1.f / sqrtf(q*(1.f/768.f) + 1e-12f);
#pragma unroll
  for (int j = 0; j < 12; ++j) {
    const int d = lane + 64*j;
    const float y = (v[j] - mean)*rstd*g[d] + bb[d];
    of[base + d] = y;
    ob[base + d] = f2b(y);
  }
}

__global__ void k_cls(const float* __restrict__ xf, const float* __restrict__ cls_w,
                      const float* __restrict__ cls_b, float* __restrict__ bscore, int n0)
{
  const int nl = blockIdx.x*4 + (threadIdx.x >> 6);
  const int lane = threadIdx.x & 63;
  const long base = (long)nl * LB * DD;
  float s = 0.f;
#pragma unroll
  for (int j = 0; j < 12; ++j) { const int d = lane + 64*j; s += xf[base + d] * cls_w[d]; }
  s = wsum(s);
  if (lane == 0) bscore[n0 + nl] = s + cls_b[0];
}

__global__ void k_final(const float* __restrict__ bscore, const int* __restrict__ selv,
                        const float* __restrict__ topk_w, float* __restrict__ out)
{
  const int b = threadIdx.x;
  if (b >= NBAT) return;
  float t0 = -3e38f, t1 = -3e38f, t2 = -3e38f;
  for (int j = 0; j < 8; ++j) {
    const float bs = bscore[b*8 + j];
    const float v = (selv[b*8 + j] != 0 && bs != 0.0f) ? bs : -9000.0f;
    if (v > t0)      { t2 = t1; t1 = t0; t0 = v; }
    else if (v > t1) { t2 = t1; t1 = v; }
    else if (v > t2) { t2 = v; }
  }
  t0 = (t0 <= -8900.0f) ? 0.0f : t0;
  t1 = (t1 <= -8900.0f) ? 0.0f : t1;
  t2 = (t2 <= -8900.0f) ? 0.0f : t2;
  out[b] = t0*topk_w[0] + t1*topk_w[1] + t2*topk_w[2];
}

extern "C" void kernel_launch(void* const* d_in, const int* in_sizes, int n_in,
                              void* d_out, int out_size, void* d_ws, size_t ws_size,
                              hipStream_t stream)
{
  const int*   query_ids  = (const int*)d_in[0];
  const int*   query_mask = (const int*)d_in[1];
  const int*   doc_ids    = (const int*)d_in[2];
  const float* word_emb   = (const float*)d_in[3];
  const float* pos_emb    = (const float*)d_in[4];
  const float* emb_ln_g   = (const float*)d_in[5];
  const float* emb_ln_b   = (const float*)d_in[6];
  const float* conv_w     = (const float*)d_in[7];
  const float* conv_b     = (const float*)d_in[8];
  const float* kernel_alpha = (const float*)d_in[9];
  const float* binw_w     = (const float*)d_in[10];
  const float* binw_b     = (const float*)d_in[11];
  const float* cls_w      = (const float*)d_in[12];
  const float* cls_b      = (const float*)d_in[13];
  const float* topk_w     = (const float*)d_in[14];
  const float* Wq  = (const float*)d_in[15];
  const float* bq  = (const float*)d_in[16];
  const float* Wk  = (const float*)d_in[17];
  const float* bk  = (const float*)d_in[18];
  const float* Wv  = (const float*)d_in[19];
  const float* bv  = (const float*)d_in[20];
  const float* Wo  = (const float*)d_in[21];
  const float* bo  = (const float*)d_in[22];
  const float* ln1_g = (const float*)d_in[23];
  const float* ln1_b = (const float*)d_in[24];
  const float* W1  = (const float*)d_in[25];
  const float* bf1 = (const float*)d_in[26];
  const float* W2  = (const float*)d_in[27];
  const float* bf2 = (const float*)d_in[28];
  const float* ln2_g = (const float*)d_in[29];
  const float* ln2_b = (const float*)d_in[30];
  (void)in_sizes; (void)n_in; (void)out_size;

  char* ws = (char*)d_ws;
  size_t o = 0;
  auto take = [&](size_t bytes) { char* p = ws + o; o += bytes; return p; };
  int*   chunks = (int*)take(655360);
  int*   valid  = (int*)take(10240);
  float* samp   = (float*)take(10240);
  int*   topidx = (int*)take(1024);
  int*   selv   = (int*)take(1024);
  int*   am     = (int*)take(96256);
  float* bscore = (float*)take(1024);
  float* qctx   = (float*)take(6291456);
  float* qkvbias= (float*)take(36864);
  u16* w3t   = (u16*)take(10616832UL);
  u16* wqkvT = (u16*)take(14155776UL);
  u16* woT   = (u16*)take(4718592UL);
  u16* w1T   = (u16*)take(18874368UL);
  u16* w2T   = (u16*)take(18874368UL);
  const size_t persist = o;

  // ---- adaptive BERT slicing by ws_size (BSL sequences per slice) ----
  int BSL_ = 64;
  if (ws_size >= persist + (size_t)(256*LB) * 21504UL)      BSL_ = 256;
  else if (ws_size >= persist + (size_t)(128*LB) * 21504UL) BSL_ = 128;
  const int NSL2_ = 256 / BSL_;
  const long M2 = (long)BSL_ * LB;

  // ---- adaptive stage-1 slicing (CSL chunk segments per slice) ----
  // per-seg bytes = 66*2304*2 (A3) + 64*768*4 (Ys) = 500,736
  int CSL_ = 256;
  if (ws_size >= persist + 512UL * 500736UL) CSL_ = 512;
  const int NSL1_ = NSEGC / CSL_;
  const int MSL1_ = CSL_ * 64;

  char* U = ws + persist;
  // stage-1 views
  u16*   A3s = (u16*)U;                                  // CSL_*66*2304*2
  float* Ys  = (float*)(U + (size_t)CSL_ * 304128UL);    // CSL_*64*768*4 (raw conv out; epi fused in cos_pool)
  // BERT views
  u16*   qkvb   = (u16*)U;                               // M2*4608
  u16*   attn_o = (u16*)U;                               // bf16 gout; aliases dead qkvb
  float* xf  = (float*)(U + (size_t)M2*4608UL);          // M2*3072
  float* x1f = (float*)(U + (size_t)M2*7680UL);          // M2*3072
  u16*   xb  = (u16*)(U + (size_t)M2*10752UL);           // M2*1536
  u16*   x1b = (u16*)(U + (size_t)M2*12288UL);           // M2*1536
  u16*   ctxb= (u16*)(U + (size_t)M2*13824UL);           // M2*1536
  u16*   hb  = (u16*)(U + (size_t)M2*15360UL);           // M2*6144 -> end M2*21504

  // ---- weight packing (tiled, coalesced; batched over layers) ----
  k_pack_w3t_tile<<<dim3(12, 12, 3), 256, 0, stream>>>(conv_w, w3t);
  k_pack_qkvbias<<<36, 256, 0, stream>>>(bq, bk, bv, qkvbias);
  k_transpose_qkvo<<<dim3(12,12,16), 256, 0, stream>>>(Wq, Wk, Wv, Wo, wqkvT, woT);
  k_transpose_w1<<<dim3(12,48,4), 256, 0, stream>>>(W1, w1T);
  k_transpose_w2<<<dim3(48,12,4), 256, 0, stream>>>(W2, w2T);

  // ---- stage 1: chunk scoring ----
  k_build_chunks<<<NSEGC, 64, 0, stream>>>(doc_ids, chunks, valid);
  k_emb_conv<<<(NBAT*66)/4, 256, 0, stream>>>(chunks, query_ids, word_emb, pos_emb, emb_ln_g, emb_ln_b,
                                              A3s, NSEGC, NBAT*66);
  gemm_mid<1,1,0><<<(NBAT*64/128)*(DD/192), 512, 0, stream>>>(A3s, w3t, qctx, nullptr, NBAT*64, DD, KC);
  k_conv_epi<<<(NBAT*64)/4, 256, 0, stream>>>(qctx, conv_b);
  for (int s = 0; s < NSL1_; ++s) {
    const int seg0 = s * CSL_;
    k_emb_conv<<<(CSL_*66+3)/4, 256, 0, stream>>>(chunks, query_ids, word_emb, pos_emb, emb_ln_g, emb_ln_b,
                                                  A3s, seg0, CSL_*66);
    gemm_mid<1,1,0><<<(MSL1_/128)*(DD/192), 512, 0, stream>>>(A3s, w3t, Ys, nullptr, MSL1_, DD, KC);
    k_cos_pool<<<CSL_, 256, 0, stream>>>(Ys, conv_b, qctx, chunks, valid, query_mask, kernel_alpha,
                                         binw_w, binw_b, samp, seg0);
  }
  k_top8<<<NBAT, 64, 0, stream>>>(samp, valid, topidx, selv);

  // ---- stage 2: BERT rerank (adaptive slices; all GEMMs on gemm_mid) ----
  for (int t = 0; t < NSL2_; ++t) {
    const int n0 = t * BSL_;
    k_bert_emb<<<(int)(M2/4), 256, 0, stream>>>(chunks, query_ids, query_mask, topidx, word_emb, pos_emb,
                                                emb_ln_g, emb_ln_b, xf, xb, am, n0);
    for (int L = 0; L < 4; ++L) {
      gemm_mid<0,0,3><<<(int)((M2/128)*(2304/192)), 512, 0, stream>>>(xb, wqkvT + (size_t)L*2304*768, qkvb, qkvbias + L*2304, (int)M2, 2304, 768);
      k_attn_mfma<<<BSL_*12, 384, 0, stream>>>(qkvb, am, ctxb, n0);
      gemm_mid<0,0,2><<<(int)((M2/128)*(768/192)), 512, 0, stream>>>(ctxb, woT + (size_t)L*768*768, attn_o, nullptr, (int)M2, 768, 768);
      k_ln<<<(int)(M2/4), 256, 0, stream>>>(xf, attn_o, bo + L*768, ln1_g + L*768, ln1_b + L*768, x1f, x1b);
      gemm_mid<0,0,1><<<(int)((M2/128)*(3072/192)), 512, 0, stream>>>(x1b, w1T + (size_t)L*3072*768, hb, bf1 + L*3072, (int)M2, 3072, 768);
      gemm_mid<0,0,2><<<(int)((M2/128)*(768/192)), 512, 0, stream>>>(hb, w2T + (size_t)L*768*3072, attn_o, nullptr, (int)M2, 768, 3072);
      k_ln<<<(int)(M2/4), 256, 0, stream>>>(x1f, attn_o, bf2 + L*768, ln2_g + L*768, ln2_b + L*768, xf, xb);
    }
    k_cls<<<BSL_/4, 256, 0, stream>>>(xf, cls_w, cls_b, bscore, n0);
  }
  k_final<<<1, 64, 0, stream>>>(bscore, selv, topk_w, (float*)d_out);
}